// Round 3
// baseline (4402.595 us; speedup 1.0000x reference)
//
#include <hip/hip_runtime.h>

// DualEncoderLSTMDense: dual peephole-LSTM encoders (shared weights) + M-projection + tiny MLP.
// B=256, L=128, E=256, H=512, VOCAB=90000, NUM_NEG=4, forget_bias=2.0.
//
// Precision design: the recurrence bifurcates (peephole positive feedback, ref logits ~488),
// so borderline units tip on tiny deterministic perturbations. Every matmul operand is
// carried as TWO bf16 planes (hi+lo, ~2^-18 relative) with 3-4 cross products => the whole
// z-matmul is fp32-faithful (~1e-7), matching the numpy fp32 reference regime. c stays fp32;
// gate transcendentals use precise libm expf/tanhf.

typedef unsigned short u16;
typedef __attribute__((ext_vector_type(8))) short  s16x8;   // 8 bf16 = one MFMA A/B fragment
typedef __attribute__((ext_vector_type(4))) float  f32x4;

#define MFMA(a, b, c) __builtin_amdgcn_mfma_f32_16x16x32_bf16((a), (b), (c), 0, 0, 0)

__device__ __forceinline__ u16 f2bf(float f) {   // RNE float -> bf16
    union { float f; unsigned u; } v; v.f = f;
    unsigned r = v.u + 0x7FFFu + ((v.u >> 16) & 1u);
    return (u16)(r >> 16);
}
__device__ __forceinline__ float bf2f(u16 h) {
    union { unsigned u; float f; } v; v.u = ((unsigned)h) << 16;
    return v.f;
}
__device__ __forceinline__ float sigm(float x) { return 1.0f / (1.0f + expf(-x)); }

// ---- transpose fp32 [R][C] -> bf16 hi/lo planes [C][R] (R,C multiples of 32) ----
__global__ __launch_bounds__(256) void transpose_split(const float* __restrict__ src,
        u16* __restrict__ dhi, u16* __restrict__ dlo, int R, int C)
{
    __shared__ float tile[32][33];
    const int bx = blockIdx.x * 32;   // src col base
    const int by = blockIdx.y * 32;   // src row base
    for (int i = threadIdx.y; i < 32; i += 8)
        tile[i][threadIdx.x] = src[(size_t)(by + i) * C + bx + threadIdx.x];
    __syncthreads();
    for (int i = threadIdx.y; i < 32; i += 8) {
        float v = tile[threadIdx.x][i];
        u16 hi = f2bf(v);
        size_t o = (size_t)(bx + i) * R + by + threadIdx.x;
        dhi[o] = hi;
        dlo[o] = f2bf(v - bf2f(hi));
    }
}

// ---- zero LSTM state: c fp32 [512][512], h0 hi/lo bf16 [512][512] ----
__global__ __launch_bounds__(256) void zero_state(float* __restrict__ c,
        u16* __restrict__ h0_hi, u16* __restrict__ h0_lo)
{
    const int i = blockIdx.x * 256 + threadIdx.x;
    c[i]     = 0.0f;
    h0_hi[i] = 0;
    h0_lo[i] = 0;
}

// ---- one LSTM timestep for both encoders (512 batch rows), fused gather+matmul+gates ----
// grid (32,8): blockIdx.x = hid tile (16 wide), blockIdx.y = row tile (64 wide); 4 waves = 4 row sub-tiles
#define GSTRIDE (512 * 768)
__global__ __launch_bounds__(256) void lstm_step(
        const float* __restrict__ emb,    // [VOCAB][256] fp32
        const int* __restrict__ qtok,     // [256][128]
        const int* __restrict__ rtok,     // [256][128]
        const u16* __restrict__ h_in_hi,  // [512][512] bf16
        const u16* __restrict__ h_in_lo,
        u16* __restrict__ h_out_hi,
        u16* __restrict__ h_out_lo,
        float* __restrict__ c,            // [512][512] fp32 (in-place)
        const u16* __restrict__ Wt_hi,    // [2048][768] bf16 (transposed lstm_kernel)
        const u16* __restrict__ Wt_lo,
        const float* __restrict__ bias, const float* __restrict__ wi,
        const float* __restrict__ wf,   const float* __restrict__ wo,
        const int* __restrict__ qlen,   const int* __restrict__ rlen, int t)
{
    const int tid  = threadIdx.x;
    const int lane = tid & 63;
    const int w    = tid >> 6;
    const int row0 = blockIdx.y * 64 + w * 16;
    const int hid0 = blockIdx.x * 16;
    const int frow = lane & 15;   // A row / B col within fragment
    const int kgrp = lane >> 4;   // k chunk: k = kgrp*8 + j

    f32x4 acc[4] = {{0,0,0,0},{0,0,0,0},{0,0,0,0},{0,0,0,0}};  // gates i,j,f,o

    const int arow = row0 + frow;
    const int tok  = (arow < 256) ? qtok[arow * 128 + t] : rtok[(arow - 256) * 128 + t];
    const float* xrow = emb + (size_t)tok * 256 + kgrp * 8;
    const u16*   a_hh = h_in_hi + arow * 512 + kgrp * 8;
    const u16*   a_hl = h_in_lo + arow * 512 + kgrp * 8;
    const int    wofs = (hid0 + frow) * 768 + kgrp * 8;

    // x part: K = 0..255, fp32 gather split into 2 planes, 3 products (residual ~1e-8)
    #pragma unroll
    for (int ks = 0; ks < 8; ++ks) {
        const float4 v0 = *(const float4*)(xrow + ks * 32);
        const float4 v1 = *(const float4*)(xrow + ks * 32 + 4);
        const float vv[8] = {v0.x, v0.y, v0.z, v0.w, v1.x, v1.y, v1.z, v1.w};
        s16x8 xh, xl;
        #pragma unroll
        for (int e = 0; e < 8; ++e) {
            const u16 hb = f2bf(vv[e]);
            xh[e] = (short)hb;
            xl[e] = (short)f2bf(vv[e] - bf2f(hb));
        }
        #pragma unroll
        for (int g = 0; g < 4; ++g) {
            const s16x8 bh = *(const s16x8*)(Wt_hi + wofs + g * GSTRIDE + ks * 32);
            const s16x8 bl = *(const s16x8*)(Wt_lo + wofs + g * GSTRIDE + ks * 32);
            acc[g] = MFMA(xh, bh, acc[g]);
            acc[g] = MFMA(xl, bh, acc[g]);
            acc[g] = MFMA(xh, bl, acc[g]);
        }
    }
    // h part: K = 256..767, 2-plane x 2-plane, all 4 products
    #pragma unroll 2
    for (int ks = 0; ks < 16; ++ks) {
        const int ko = ks * 32;
        const s16x8 ah = *(const s16x8*)(a_hh + ko);
        const s16x8 al = *(const s16x8*)(a_hl + ko);
        #pragma unroll
        for (int g = 0; g < 4; ++g) {
            const s16x8 bh = *(const s16x8*)(Wt_hi + wofs + g * GSTRIDE + 256 + ko);
            const s16x8 bl = *(const s16x8*)(Wt_lo + wofs + g * GSTRIDE + 256 + ko);
            acc[g] = MFMA(ah, bh, acc[g]);
            acc[g] = MFMA(al, bh, acc[g]);
            acc[g] = MFMA(ah, bl, acc[g]);
            acc[g] = MFMA(al, bl, acc[g]);
        }
    }

    // gates + peepholes + masking (lane-local: this block owns these (row,hid) outputs)
    const int   ohid = hid0 + frow;
    const float bi  = bias[ohid];
    const float bj  = bias[512 + ohid];
    const float bff = bias[1024 + ohid];
    const float bo  = bias[1536 + ohid];
    const float wiv = wi[ohid], wfv = wf[ohid], wov = wo[ohid];
    #pragma unroll
    for (int r = 0; r < 4; ++r) {
        const int   row  = row0 + kgrp * 4 + r;
        const int   off  = row * 512 + ohid;
        const float cold = c[off];
        const float ig = sigm(acc[0][r] + bi + wiv * cold);
        const float jg = tanhf(acc[1][r] + bj);
        const float fg = sigm(acc[2][r] + bff + wfv * cold + 2.0f);
        const float cn = fg * cold + ig * jg;
        const float og = sigm(acc[3][r] + bo + wov * cn);
        const float hn = og * tanhf(cn);
        const int   len = (row < 256) ? qlen[row] : rlen[row - 256];
        if (t < len) {
            c[off] = cn;
            const u16 hi = f2bf(hn);
            h_out_hi[off] = hi;
            h_out_lo[off] = f2bf(hn - bf2f(hi));
        } else {
            h_out_hi[off] = h_in_hi[off];
            h_out_lo[off] = h_in_lo[off];
        }
    }
}

// ---- qt[256][512] = q_h @ M (MFMA, both operands hi+lo, 4 products) ; grid (8,16), 4 waves 2x2 ----
__global__ __launch_bounds__(256) void qt_kernel(
        const u16* __restrict__ h_hi, const u16* __restrict__ h_lo,
        const u16* __restrict__ Mt_hi, const u16* __restrict__ Mt_lo, float* __restrict__ qt)
{
    const int tid = threadIdx.x, lane = tid & 63, w = tid >> 6;
    const int wr = w >> 1, wc = w & 1;
    const int row0 = blockIdx.x * 32 + wr * 16;
    const int col0 = blockIdx.y * 32 + wc * 16;
    const int frow = lane & 15, kgrp = lane >> 4;
    f32x4 acc = {0, 0, 0, 0};
    const u16* aph = h_hi  + (row0 + frow) * 512 + kgrp * 8;
    const u16* apl = h_lo  + (row0 + frow) * 512 + kgrp * 8;
    const u16* bph = Mt_hi + (col0 + frow) * 512 + kgrp * 8;
    const u16* bpl = Mt_lo + (col0 + frow) * 512 + kgrp * 8;
    #pragma unroll 4
    for (int ks = 0; ks < 16; ++ks) {
        s16x8 ah = *(const s16x8*)(aph + ks * 32);
        s16x8 al = *(const s16x8*)(apl + ks * 32);
        s16x8 bh = *(const s16x8*)(bph + ks * 32);
        s16x8 bl = *(const s16x8*)(bpl + ks * 32);
        acc = MFMA(ah, bh, acc);
        acc = MFMA(al, bh, acc);
        acc = MFMA(ah, bl, acc);
        acc = MFMA(al, bl, acc);
    }
    #pragma unroll
    for (int r = 0; r < 4; ++r)
        qt[(row0 + kgrp * 4 + r) * 512 + col0 + frow] = acc[r];
}

// ---- final MLP: 1280 rows, one wave per row ----
__global__ __launch_bounds__(256) void dense_out(const float* __restrict__ qt,
        const u16* __restrict__ h_hi, const u16* __restrict__ h_lo,
        const float* __restrict__ W1, const float* __restrict__ b1,
        const float* __restrict__ W2, const float* __restrict__ b2, float* __restrict__ out)
{
    const int r    = blockIdx.x * 4 + (threadIdx.x >> 6);
    const int lane = threadIdx.x & 63;
    int qi, ri;
    if (r < 256) { qi = r; ri = r; }
    else { const int g = (r - 256) >> 8; const int b = (r - 256) & 255; qi = b; ri = (b + g + 1) & 255; }

    float p[10];
    #pragma unroll
    for (int u = 0; u < 10; ++u) p[u] = 0.0f;
    for (int k = lane; k < 512; k += 64) {
        const float xq = qt[qi * 512 + k];
        #pragma unroll
        for (int u = 0; u < 10; ++u) p[u] += xq * W1[k * 10 + u];
    }
    for (int k = lane; k < 512; k += 64) {
        const int off = (256 + ri) * 512 + k;
        const float xr = bf2f(h_hi[off]) + bf2f(h_lo[off]);
        #pragma unroll
        for (int u = 0; u < 10; ++u) p[u] += xr * W1[(512 + k) * 10 + u];
    }
    #pragma unroll
    for (int off = 32; off; off >>= 1) {
        #pragma unroll
        for (int u = 0; u < 10; ++u) p[u] += __shfl_xor(p[u], off);
    }
    float s = b2[0];
    #pragma unroll
    for (int u = 0; u < 10; ++u) {
        const float h1 = fmaxf(p[u] + b1[u], 0.0f);
        s += h1 * W2[u];
    }
    if (lane == 0) out[r] = fmaxf(s, 0.0f);
}

extern "C" void kernel_launch(void* const* d_in, const int* in_sizes, int n_in,
                              void* d_out, int out_size, void* d_ws, size_t ws_size,
                              hipStream_t stream)
{
    const float* emb  = (const float*)d_in[0];
    const float* Wk   = (const float*)d_in[1];
    const float* bias = (const float*)d_in[2];
    const float* wi   = (const float*)d_in[3];
    const float* wf   = (const float*)d_in[4];
    const float* wo   = (const float*)d_in[5];
    const float* M    = (const float*)d_in[6];
    const float* W1   = (const float*)d_in[7];
    const float* b1   = (const float*)d_in[8];
    const float* W2   = (const float*)d_in[9];
    const float* b2   = (const float*)d_in[10];
    const int*   qtok = (const int*)d_in[11];
    const int*   rtok = (const int*)d_in[12];
    const int*   qlen = (const int*)d_in[13];
    const int*   rlen = (const int*)d_in[14];
    float* out = (float*)d_out;

    // workspace layout (16B-aligned); total 11,010,048 B (~10.5 MB)
    char* ws = (char*)d_ws;
    u16*   Wt_hi = (u16*)(ws + 0);            // 2048*768*2  = 3,145,728
    u16*   Wt_lo = (u16*)(ws + 3145728);      //               3,145,728
    u16*   Mt_hi = (u16*)(ws + 6291456);      // 512*512*2   =   524,288
    u16*   Mt_lo = (u16*)(ws + 6815744);      //                 524,288
    u16*   h0_hi = (u16*)(ws + 7340032);      //                 524,288
    u16*   h0_lo = (u16*)(ws + 7864320);      //                 524,288
    u16*   h1_hi = (u16*)(ws + 8388608);      //                 524,288
    u16*   h1_lo = (u16*)(ws + 8912896);      //                 524,288
    float* c     = (float*)(ws + 9437184);    // 512*512*4   = 1,048,576
    float* qt    = (float*)(ws + 10485760);   //                 524,288

    transpose_split<<<dim3(64, 24), dim3(32, 8), 0, stream>>>(Wk, Wt_hi, Wt_lo, 768, 2048);
    transpose_split<<<dim3(16, 16), dim3(32, 8), 0, stream>>>(M, Mt_hi, Mt_lo, 512, 512);
    zero_state<<<1024, 256, 0, stream>>>(c, h0_hi, h0_lo);

    const u16* hin_hi = h0_hi; const u16* hin_lo = h0_lo;
    u16* hout_hi = h1_hi;      u16* hout_lo = h1_lo;
    for (int t = 0; t < 128; ++t) {
        lstm_step<<<dim3(32, 8), 256, 0, stream>>>(emb, qtok, rtok,
                                                   hin_hi, hin_lo, hout_hi, hout_lo, c,
                                                   Wt_hi, Wt_lo, bias, wi, wf, wo, qlen, rlen, t);
        const u16* th = hin_hi; hin_hi = hout_hi; hout_hi = (u16*)th;
        const u16* tl = hin_lo; hin_lo = hout_lo; hout_lo = (u16*)tl;
    }

    qt_kernel<<<dim3(8, 16), 256, 0, stream>>>(hin_hi, hin_lo, Mt_hi, Mt_lo, qt);
    dense_out<<<320, 256, 0, stream>>>(qt, hin_hi, hin_lo, W1, b1, W2, b2, out);
}